// Round 9
// baseline (438.861 us; speedup 1.0000x reference)
//
#include <hip/hip_runtime.h>
#include <math.h>

#define NN 4096
#define LN_EPS 1e-5f
#define EPS 1e-8f

typedef unsigned short ushortT;
typedef unsigned int uintT;
typedef __attribute__((ext_vector_type(8))) short short8;
typedef __attribute__((ext_vector_type(4))) float f32x4;
typedef __attribute__((ext_vector_type(4))) unsigned short us4;

// workspace offsets (in floats)
#define OFF_KT    0L
#define OFF_V     16777216L
#define OFF_QT    33554432L
#define OFF_PART  33587200L   // part [b][blk=16][8][64] f32   524288
#define OFF_PCOL  34111488L   // pcol [b][blk=16][8] f32       8192
#define OFF_SLOTS 34119680L   // slots [b][k][d] f32           32768
#define OFF_WIHT  34152448L   // w_ih^T [64][192]              12288
#define OFF_WHHT  34164736L   // w_hh^T [64][192]              12288
#define OFF_W1T   34177024L   // mlp_w1^T [64][128]            8192
#define OFF_W2T   34185216L   // mlp_w2^T [128][64]            8192
#define OFF_WQT   34193408L   // Wq^T [64][64]                 4096
#define OFF_WKV   34197504L   // wpack bf16 MFMA B-frags       8192 ushorts
#define OFF_CNT   34201600L   // [64][32] counters + [64][32] flags (4096 ints)

__device__ __forceinline__ float wredsum(float v) {
#pragma unroll
  for (int off = 32; off > 0; off >>= 1) v += __shfl_xor(v, off);
  return v;
}

__device__ __forceinline__ ushortT f2bf(float f) {
  uintT b = __float_as_uint(f);
  b += 0x7fff + ((b >> 16) & 1);          // RNE
  return (ushortT)(b >> 16);
}

// ---------------------------------------------------------------------------
// K0: merged weight prep + slots init. grid 208 x 256.
__global__ __launch_bounds__(256) void k_setup(
    const float* __restrict__ w_ih, const float* __restrict__ w_hh,
    const float* __restrict__ w1, const float* __restrict__ w2,
    const float* __restrict__ Wq,
    const float* __restrict__ Wk, const float* __restrict__ Wv,
    const float* __restrict__ noise, const float* __restrict__ smu,
    const float* __restrict__ slsig,
    const float* __restrict__ g_sl, const float* __restrict__ b_sl,
    float* __restrict__ wihT, float* __restrict__ whhT,
    float* __restrict__ w1T, float* __restrict__ w2T, float* __restrict__ wqT,
    ushortT* __restrict__ wpack,
    float* __restrict__ slots, ushortT* __restrict__ qF,
    int* __restrict__ cnt)
{
  const int tid = threadIdx.x;
  int idx = blockIdx.x * 256 + tid;
  if (idx < 12288) {
    int j = idx >> 6, f = idx & 63;
    wihT[f * 192 + j] = w_ih[idx];
  } else if (idx < 24576) {
    int i = idx - 12288; int j = i >> 6, f = i & 63;
    whhT[f * 192 + j] = w_hh[i];
  } else if (idx < 32768) {
    int i = idx - 24576; int j = i >> 6, f = i & 63;
    w1T[f * 128 + j] = w1[i];
  } else if (idx < 40960) {
    int i = idx - 32768; int d = i >> 7, j = i & 127;
    w2T[j * 64 + d] = w2[i];
  } else if (idx < 45056) {
    int i = idx - 40960; int e = i >> 6, d = i & 63;
    wqT[d * 64 + e] = Wq[i];
  } else if (idx < 53248) {
    int i = idx - 45056;                 // 0..8191
    int j = i & 7, l = (i >> 3) & 63, t2 = i >> 9;
    int ct = t2 >> 1, kb = t2 & 1;
    int kf = kb * 32 + ((l >> 4) << 3) + j;
    int col = (ct << 4) | (l & 15);
    float val = (col < 64) ? Wk[col * 64 + kf] : Wv[(col - 64) * 64 + kf];
    wpack[i] = f2bf(val);
  }

  if (blockIdx.x >= 128) {
    // blocks 128..143 zero counters + flags (4096 ints)
    if (blockIdx.x < 144) cnt[(blockIdx.x - 128) * 256 + tid] = 0;
    return;
  }

  __shared__ float WqS[64 * 65];   // [d][e]
  __shared__ float S[4][64];
  const int lane = tid & 63, wave = tid >> 6;
  const int row = blockIdx.x * 4 + wave;   // 0..511
  const int b = row >> 3, ks = row & 7;

#pragma unroll
  for (int i = 0; i < 16; ++i) {
    int ii = tid + i * 256;
    int e = ii >> 6, d = ii & 63;
    WqS[d * 65 + e] = Wq[ii];
  }

  float s0 = fmaf(expf(slsig[lane]), noise[row * 64 + lane], smu[lane]);
  slots[row * 64 + lane] = s0;

  float mu = wredsum(s0) * (1.f / 64.f);
  float dx = s0 - mu;
  float var = wredsum(dx * dx) * (1.f / 64.f);
  float sn = dx * rsqrtf(var + LN_EPS) * g_sl[lane] + b_sl[lane];
  S[wave][lane] = sn;
  __syncthreads();
  float qe = 0.f;
#pragma unroll 16
  for (int d = 0; d < 64; ++d) qe = fmaf(S[wave][d], WqS[d * 65 + lane], qe);
  const int kb = lane >> 5, lrow = (lane & 31) >> 3, j = lane & 7;
  qF[((((b * 2 + kb) << 6) + (lrow << 4) + ks) << 3) + j] = f2bf(qe * 0.125f);
  qF[((((b * 2 + kb) << 6) + (lrow << 4) + 8 + ks) << 3) + j] = 0;
}

// ---------------------------------------------------------------------------
// K1: fused LayerNorm + K/V projection via bf16 MFMA, fragment-order output.
__global__ __launch_bounds__(256, 4) void k_ln_project(
    const float* __restrict__ inp, const ushortT* __restrict__ wpack,
    const float* __restrict__ g, const float* __restrict__ bbv,
    ushortT* __restrict__ ktF, ushortT* __restrict__ vF)
{
  __shared__ __align__(16) ushortT xnF[4096];   // [frag8][lane64][j8]
  __shared__ __align__(16) ushortT kS[4096];    // k frags staging
  const int tid = threadIdx.x;
  const int lane = tid & 63;
  const int wave = tid >> 6;
  const int l15 = lane & 15, q = lane >> 4;
  const int tile = blockIdx.x;
  const int b = tile >> 6;
  const int c = tile & 63;
  const int n0 = c << 6;
  const float* rowbase = inp + (((long)b * NN + n0) << 6);
  const float4 g4 = *(const float4*)&g[l15 << 2];
  const float4 b4 = *(const float4*)&bbv[l15 << 2];

#pragma unroll
  for (int i = 0; i < 4; ++i) {
    const int row = (wave << 4) + (i << 2) + q;
    float4 x = *(const float4*)&rowbase[(row << 6) + (l15 << 2)];
    float s = x.x + x.y + x.z + x.w;
    float s2 = fmaf(x.x, x.x, fmaf(x.y, x.y, fmaf(x.z, x.z, x.w * x.w)));
    s += __shfl_xor(s, 1);  s2 += __shfl_xor(s2, 1);
    s += __shfl_xor(s, 2);  s2 += __shfl_xor(s2, 2);
    s += __shfl_xor(s, 4);  s2 += __shfl_xor(s2, 4);
    s += __shfl_xor(s, 8);  s2 += __shfl_xor(s2, 8);
    const float mu = s * (1.f / 64.f);
    const float var = fmaf(-mu, mu, s2 * (1.f / 64.f));
    const float rs = rsqrtf(var + LN_EPS);
    us4 p = {f2bf((x.x - mu) * rs * g4.x + b4.x), f2bf((x.y - mu) * rs * g4.y + b4.y),
             f2bf((x.z - mu) * rs * g4.z + b4.z), f2bf((x.w - mu) * rs * g4.w + b4.w)};
    *(us4*)&xnF[((((wave << 1) + (l15 >> 3)) << 6) + (((l15 & 7) >> 1) << 4)
                 + (row & 15)) * 8 + ((l15 & 1) << 2)] = p;
  }

  short8 bfrag[2][2];
#pragma unroll
  for (int nt = 0; nt < 2; ++nt)
#pragma unroll
    for (int kb = 0; kb < 2; ++kb)
      bfrag[nt][kb] = *(const short8*)&wpack[((((2 * wave + nt) << 1) | kb) * 64 + lane) << 3];

  __syncthreads();

  f32x4 acc[4][2];
#pragma unroll
  for (int mt = 0; mt < 4; ++mt)
#pragma unroll
    for (int nt = 0; nt < 2; ++nt) acc[mt][nt] = (f32x4){0.f, 0.f, 0.f, 0.f};

#pragma unroll
  for (int mt = 0; mt < 4; ++mt) {
    short8 a0 = *(const short8*)&xnF[((mt * 2 + 0) * 64 + lane) << 3];
    short8 a1 = *(const short8*)&xnF[((mt * 2 + 1) * 64 + lane) << 3];
#pragma unroll
    for (int nt = 0; nt < 2; ++nt) {
      acc[mt][nt] = __builtin_amdgcn_mfma_f32_16x16x32_bf16(a0, bfrag[nt][0], acc[mt][nt], 0, 0, 0);
      acc[mt][nt] = __builtin_amdgcn_mfma_f32_16x16x32_bf16(a1, bfrag[nt][1], acc[mt][nt], 0, 0, 0);
    }
  }

  if (wave < 2) {
#pragma unroll
    for (int mt = 0; mt < 4; ++mt)
#pragma unroll
      for (int nt = 0; nt < 2; ++nt) {
        const int base = (((mt * 2 + wave) << 6) + ((2 * nt + (l15 >> 3)) << 4) + (q << 2));
#pragma unroll
        for (int r = 0; r < 4; ++r)
          kS[((base + r) << 3) + (l15 & 7)] = f2bf(acc[mt][nt][r]);
      }
  } else {
    ushortT* vbase = vF + ((long)(b * 64 + c) << 12);
#pragma unroll
    for (int mt = 0; mt < 4; ++mt)
#pragma unroll
      for (int nt = 0; nt < 2; ++nt) {
        const int ntg = 2 * (wave - 2) + nt;
        us4 p = {f2bf(acc[mt][nt][0]), f2bf(acc[mt][nt][1]),
                 f2bf(acc[mt][nt][2]), f2bf(acc[mt][nt][3])};
        *(us4*)&vbase[(((((ntg << 1) + (mt >> 1)) << 6)
                        + (((mt & 1) * 2 + (q >> 1)) << 4) + l15) << 3)
                      + ((q & 1) << 2)] = p;
      }
  }
  __syncthreads();

  ushortT* kdst = ktF + ((long)(b * 64 + c) << 12);
  short8 v0 = *(const short8*)&kS[tid << 4];
  short8 v1 = *(const short8*)&kS[(tid << 4) + 8];
  *(short8*)&kdst[tid << 4] = v0;
  *(short8*)&kdst[(tid << 4) + 8] = v1;
}

// ---------------------------------------------------------------------------
// K2: persistent fused attention — all 3 iterations in one launch.
// k/v frags register-resident. Iteration boundary: batch-local flag spin;
// updater publishes slots via agent-scope stores; all blocks recompute q
// locally from coherent slots. grid 1024 x 256, 4 blocks/CU co-resident.
__global__ __launch_bounds__(256, 4) void k_attn_iter(
    const ushortT* __restrict__ ktF, const ushortT* __restrict__ vF,
    const ushortT* __restrict__ qF,
    float* __restrict__ part, float* __restrict__ pcol, int* __restrict__ cnt,
    float* __restrict__ slots,
    const float* __restrict__ wihT, const float* __restrict__ whhT,
    const float* __restrict__ w1T, const float* __restrict__ w2T,
    const float* __restrict__ wqT,
    const float* __restrict__ b_ih, const float* __restrict__ b_hh,
    const float* __restrict__ mb1, const float* __restrict__ mb2,
    const float* __restrict__ g_ml, const float* __restrict__ b_ml,
    const float* __restrict__ g_sl, const float* __restrict__ b_sl,
    float* __restrict__ dout)
{
  __shared__ __align__(16) ushortT attnF[4][1024];  // P A-frags / accR reuse
  __shared__ float redLds[4][512];                  // accLds / q scratch / Sw
  __shared__ float colLds[4][8];
  __shared__ int flagS;
  const int tid = threadIdx.x;
  const int lane = tid & 63;
  const int wave = tid >> 6;
  const int l15 = lane & 15, q = lane >> 4;
  const int b = blockIdx.x >> 4;
  const int i16 = blockIdx.x & 15;
  const int chunk = (i16 << 2) | wave;  // 0..63

  const ushortT* kbF = ktF + ((long)(b * 64 + chunk) << 12);
  const ushortT* vbF = vF + ((long)(b * 64 + chunk) << 12);
  int* cnt_b = &cnt[b << 5];
  int* flg_b = &cnt[2048 + (b << 5)];
  const float gsl = g_sl[lane], bsl = b_sl[lane];

  // persistent fragments (reused all 3 iterations)
  short8 kA[4][2];
#pragma unroll
  for (int mt = 0; mt < 4; ++mt)
#pragma unroll
    for (int kb = 0; kb < 2; ++kb)
      kA[mt][kb] = *(const short8*)&kbF[((mt * 2 + kb) * 64 + lane) << 3];
  short8 vB[4][2];
#pragma unroll
  for (int nt = 0; nt < 4; ++nt)
#pragma unroll
    for (int ks = 0; ks < 2; ++ks)
      vB[nt][ks] = *(const short8*)&vbF[((nt * 2 + ks) * 64 + lane) << 3];

  for (int it = 0; it < 3; ++it) {
    short8 qB[2];
    if (it == 0) {
#pragma unroll
      for (int kb = 0; kb < 2; ++kb)
        qB[kb] = *(const short8*)&qF[(((b * 2 + kb) << 6) + lane) << 3];
    } else {
      // wait for this batch's slots(it) to be published
      if (tid == 0) {
        while (__hip_atomic_load(flg_b, __ATOMIC_RELAXED, __HIP_MEMORY_SCOPE_AGENT) < it)
          __builtin_amdgcn_s_sleep(2);
      }
      __syncthreads();
      // recompute q from coherent slots: each wave handles 2 slot rows
      float* qsq  = &redLds[0][0];   // [ks][d] LN_slots(slots)
      float* qLds = &redLds[2][0];   // [ks][e] q * 0.125
      const int ksA = wave * 2, ksB = ksA + 1;
      float sA = __hip_atomic_load(&slots[(b * 8 + ksA) * 64 + lane],
                                   __ATOMIC_RELAXED, __HIP_MEMORY_SCOPE_AGENT);
      float sB = __hip_atomic_load(&slots[(b * 8 + ksB) * 64 + lane],
                                   __ATOMIC_RELAXED, __HIP_MEMORY_SCOPE_AGENT);
      float ta = sA, tb = sB;
#pragma unroll
      for (int off = 32; off > 0; off >>= 1) { ta += __shfl_xor(ta, off); tb += __shfl_xor(tb, off); }
      const float muA = ta * (1.f / 64.f), muB = tb * (1.f / 64.f);
      const float dxA = sA - muA, dxB = sB - muB;
      float va = dxA * dxA, vb = dxB * dxB;
#pragma unroll
      for (int off = 32; off > 0; off >>= 1) { va += __shfl_xor(va, off); vb += __shfl_xor(vb, off); }
      qsq[ksA * 64 + lane] = dxA * rsqrtf(va * (1.f / 64.f) + LN_EPS) * gsl + bsl;
      qsq[ksB * 64 + lane] = dxB * rsqrtf(vb * (1.f / 64.f) + LN_EPS) * gsl + bsl;
      __syncthreads();
      float qeA = 0.f, qeB = 0.f;
#pragma unroll 8
      for (int d = 0; d < 64; ++d) {
        const float w = wqT[d * 64 + lane];
        qeA = fmaf(qsq[ksA * 64 + d], w, qeA);
        qeB = fmaf(qsq[ksB * 64 + d], w, qeB);
      }
      qLds[ksA * 64 + lane] = qeA * 0.125f;
      qLds[ksB * 64 + lane] = qeB * 0.125f;
      __syncthreads();
      // build B-frags: element (l,j,kb) = q[col=l15][e=kb*32+(l>>4)*8+j], col<8
#pragma unroll
      for (int kb = 0; kb < 2; ++kb) {
        short8 v = (short8){0, 0, 0, 0, 0, 0, 0, 0};
        if (l15 < 8) {
          const int e0 = (kb << 5) + (q << 3);
          float4 f0 = *(const float4*)&qLds[l15 * 64 + e0];
          float4 f1 = *(const float4*)&qLds[l15 * 64 + e0 + 4];
          v[0] = (short)f2bf(f0.x); v[1] = (short)f2bf(f0.y);
          v[2] = (short)f2bf(f0.z); v[3] = (short)f2bf(f0.w);
          v[4] = (short)f2bf(f1.x); v[5] = (short)f2bf(f1.y);
          v[6] = (short)f2bf(f1.z); v[7] = (short)f2bf(f1.w);
        }
        qB[kb] = v;
      }
      __syncthreads();   // qLds reads done before redLds reused as accLds
    }

    // ---- attention ----
    f32x4 accL[4];
#pragma unroll
    for (int mt = 0; mt < 4; ++mt) {
      accL[mt] = (f32x4){0.f, 0.f, 0.f, 0.f};
      accL[mt] = __builtin_amdgcn_mfma_f32_16x16x32_bf16(kA[mt][0], qB[0], accL[mt], 0, 0, 0);
      accL[mt] = __builtin_amdgcn_mfma_f32_16x16x32_bf16(kA[mt][1], qB[1], accL[mt], 0, 0, 0);
    }

    float csum = 0.f;
#pragma unroll
    for (int mt = 0; mt < 4; ++mt) {
      float av[4];
#pragma unroll
      for (int r = 0; r < 4; ++r) {
        float ev = __expf(accL[mt][r]);
        float sv = ev;
        sv += __shfl_xor(sv, 1); sv += __shfl_xor(sv, 2); sv += __shfl_xor(sv, 4);
        float a = ev * (1.f / sv) + EPS;
        av[r] = a;
        csum += a;
      }
      us4 p = {f2bf(av[0]), f2bf(av[1]), f2bf(av[2]), f2bf(av[3])};
      *(us4*)&attnF[wave][((((mt >> 1) << 6) + (((mt & 1) * 2 + (q >> 1)) << 4)
                            + l15) << 3) + ((q & 1) << 2)] = p;
    }
    csum += __shfl_xor(csum, 16);
    csum += __shfl_xor(csum, 32);

    short8 pA0 = *(const short8*)&attnF[wave][(0 * 64 + lane) << 3];
    short8 pA1 = *(const short8*)&attnF[wave][(1 * 64 + lane) << 3];

    f32x4 accP[4];
#pragma unroll
    for (int nt = 0; nt < 4; ++nt) {
      accP[nt] = (f32x4){0.f, 0.f, 0.f, 0.f};
      accP[nt] = __builtin_amdgcn_mfma_f32_16x16x32_bf16(pA0, vB[nt][0], accP[nt], 0, 0, 0);
      accP[nt] = __builtin_amdgcn_mfma_f32_16x16x32_bf16(pA1, vB[nt][1], accP[nt], 0, 0, 0);
    }

    float (*accLds)[8][64] = (float (*)[8][64])redLds;
    if (q < 2) {
#pragma unroll
      for (int nt = 0; nt < 4; ++nt)
#pragma unroll
        for (int r = 0; r < 4; ++r)
          accLds[wave][q * 4 + r][nt * 16 + l15] = accP[nt][r];
    }
    if (q == 0 && l15 < 8) colLds[wave][l15] = csum;
    __syncthreads();

    float* myPart = part + ((long)(b * 16 + i16) << 9);
#pragma unroll
    for (int r = 0; r < 2; ++r) {
      const int o = tid + r * 256;
      const int kk = o >> 6, d = o & 63;
      float s = accLds[0][kk][d] + accLds[1][kk][d] + accLds[2][kk][d] + accLds[3][kk][d];
      __hip_atomic_store(&myPart[o], s, __ATOMIC_RELAXED, __HIP_MEMORY_SCOPE_AGENT);
    }
    if (tid < 8) {
      float s = colLds[0][tid] + colLds[1][tid] + colLds[2][tid] + colLds[3][tid];
      __hip_atomic_store(&pcol[(b * 16 + i16) * 8 + tid], s,
                         __ATOMIC_RELAXED, __HIP_MEMORY_SCOPE_AGENT);
    }

    asm volatile("s_waitcnt vmcnt(0) lgkmcnt(0)" ::: "memory");
    __syncthreads();
    if (tid == 0) {
      int old = atomicAdd(cnt_b, 1);
      flagS = (old == it * 16 + 15);
    }
    __syncthreads();

    if (flagS) {
      // ---- updater: sum partials, GRU->LN->MLP->residual ----
      float* accR = (float*)&attnF[0][0];
      float* csR  = accR + 512;
      const float* partB = part + ((long)b << 13);
#pragma unroll
      for (int r = 0; r < 2; ++r) {
        const int o = tid + r * 256;
        float s = 0.f;
#pragma unroll
        for (int i = 0; i < 16; ++i)
          s += __hip_atomic_load(&partB[(i << 9) + o], __ATOMIC_RELAXED, __HIP_MEMORY_SCOPE_AGENT);
        accR[o] = s;
      }
      if (tid < 8) {
        float s = 0.f;
#pragma unroll
        for (int i = 0; i < 16; ++i)
          s += __hip_atomic_load(&pcol[(b * 16 + i) * 8 + tid], __ATOMIC_RELAXED, __HIP_MEMORY_SCOPE_AGENT);
        csR[tid] = s;
      }
      __syncthreads();

      float* SwA = &redLds[wave][0];
      float* SwB = &redLds[wave][256];
      const int ksA = wave * 2, ksB = ksA + 1;
      const int rowA = b * 8 + ksA, rowB = b * 8 + ksB;

      const float bir = b_ih[lane], biz = b_ih[64 + lane], bin_ = b_ih[128 + lane];
      const float bhr = b_hh[lane], bhz = b_hh[64 + lane], bhn = b_hh[128 + lane];
      const float m1a = mb1[lane], m1b = mb1[64 + lane];
      const float m2v = mb2[lane];
      const float gml = g_ml[lane], bml = b_ml[lane];

      const float u0 = accR[ksA * 64 + lane] / csR[ksA];
      const float u1 = accR[ksB * 64 + lane] / csR[ksB];
      const float h0 = __hip_atomic_load(&slots[rowA * 64 + lane], __ATOMIC_RELAXED, __HIP_MEMORY_SCOPE_AGENT);
      const float h1 = __hip_atomic_load(&slots[rowB * 64 + lane], __ATOMIC_RELAXED, __HIP_MEMORY_SCOPE_AGENT);
      SwA[lane] = u0; SwA[64 + lane] = h0;
      SwB[lane] = u1; SwB[64 + lane] = h1;

      float gir0 = bir, giz0 = biz, gin0 = bin_, ghr0 = bhr, ghz0 = bhz, ghn0 = bhn;
      float gir1 = bir, giz1 = biz, gin1 = bin_, ghr1 = bhr, ghz1 = bhz, ghn1 = bhn;
#pragma unroll 8
      for (int f = 0; f < 64; ++f) {
        const float wr = wihT[f * 192 + lane], wz = wihT[f * 192 + 64 + lane],
                    wn = wihT[f * 192 + 128 + lane];
        const float vr = whhT[f * 192 + lane], vz = whhT[f * 192 + 64 + lane],
                    vn = whhT[f * 192 + 128 + lane];
        const float uA = SwA[f], hA = SwA[64 + f];
        const float uB = SwB[f], hB = SwB[64 + f];
        gir0 = fmaf(uA, wr, gir0); giz0 = fmaf(uA, wz, giz0); gin0 = fmaf(uA, wn, gin0);
        ghr0 = fmaf(hA, vr, ghr0); ghz0 = fmaf(hA, vz, ghz0); ghn0 = fmaf(hA, vn, ghn0);
        gir1 = fmaf(uB, wr, gir1); giz1 = fmaf(uB, wz, giz1); gin1 = fmaf(uB, wn, gin1);
        ghr1 = fmaf(hB, vr, ghr1); ghz1 = fmaf(hB, vz, ghz1); ghn1 = fmaf(hB, vn, ghn1);
      }
      const float r0 = 1.f / (1.f + expf(-(gir0 + ghr0)));
      const float z0 = 1.f / (1.f + expf(-(giz0 + ghz0)));
      const float n0v = tanhf(fmaf(r0, ghn0, gin0));
      const float hnew0 = (1.f - z0) * n0v + z0 * h0;
      const float r1 = 1.f / (1.f + expf(-(gir1 + ghr1)));
      const float z1 = 1.f / (1.f + expf(-(giz1 + ghz1)));
      const float n1v = tanhf(fmaf(r1, ghn1, gin1));
      const float hnew1 = (1.f - z1) * n1v + z1 * h1;

      float sa = hnew0, sb = hnew1;
#pragma unroll
      for (int off = 32; off > 0; off >>= 1) { sa += __shfl_xor(sa, off); sb += __shfl_xor(sb, off); }
      const float muA = sa * (1.f / 64.f), muB = sb * (1.f / 64.f);
      float dxA = hnew0 - muA, dxB = hnew1 - muB;
      float va = dxA * dxA, vb = dxB * dxB;
#pragma unroll
      for (int off = 32; off > 0; off >>= 1) { va += __shfl_xor(va, off); vb += __shfl_xor(vb, off); }
      SwA[128 + lane] = dxA * rsqrtf(va * (1.f / 64.f) + LN_EPS) * gml + bml;
      SwB[128 + lane] = dxB * rsqrtf(vb * (1.f / 64.f) + LN_EPS) * gml + bml;

      float h1a0 = m1a, h1b0 = m1b, h1a1 = m1a, h1b1 = m1b;
#pragma unroll 8
      for (int f = 0; f < 64; ++f) {
        const float wA = w1T[f * 128 + lane], wB = w1T[f * 128 + 64 + lane];
        const float lA = SwA[128 + f], lB = SwB[128 + f];
        h1a0 = fmaf(lA, wA, h1a0); h1b0 = fmaf(lA, wB, h1b0);
        h1a1 = fmaf(lB, wA, h1a1); h1b1 = fmaf(lB, wB, h1b1);
      }
      SwA[lane] = fmaxf(h1a0, 0.f); SwA[64 + lane] = fmaxf(h1b0, 0.f);
      SwB[lane] = fmaxf(h1a1, 0.f); SwB[64 + lane] = fmaxf(h1b1, 0.f);

      float o0 = m2v, o1 = m2v;
#pragma unroll 8
      for (int j = 0; j < 128; ++j) {
        const float w = w2T[j * 64 + lane];
        o0 = fmaf(SwA[j], w, o0);
        o1 = fmaf(SwB[j], w, o1);
      }
      const float snew0 = hnew0 + o0;
      const float snew1 = hnew1 + o1;

      if (it == 2) {
        dout[rowA * 64 + lane] = snew0;
        dout[rowB * 64 + lane] = snew1;
      } else {
        __hip_atomic_store(&slots[rowA * 64 + lane], snew0, __ATOMIC_RELAXED, __HIP_MEMORY_SCOPE_AGENT);
        __hip_atomic_store(&slots[rowB * 64 + lane], snew1, __ATOMIC_RELAXED, __HIP_MEMORY_SCOPE_AGENT);
        asm volatile("s_waitcnt vmcnt(0) lgkmcnt(0)" ::: "memory");
        __syncthreads();
        if (tid == 0)
          __hip_atomic_store(flg_b, it + 1, __ATOMIC_RELAXED, __HIP_MEMORY_SCOPE_AGENT);
      }
    }
    if (it == 2) break;   // non-updaters done after arrival; updater wrote dout
  }
}

// ---------------------------------------------------------------------------
extern "C" void kernel_launch(void* const* d_in, const int* in_sizes, int n_in,
                              void* d_out, int out_size, void* d_ws, size_t ws_size,
                              hipStream_t stream) {
  const float* inp   = (const float*)d_in[0];
  const float* noise = (const float*)d_in[1];
  const float* smu   = (const float*)d_in[2];
  const float* slsig = (const float*)d_in[3];
  const float* Wq    = (const float*)d_in[4];
  const float* Wk    = (const float*)d_in[5];
  const float* Wv    = (const float*)d_in[6];
  const float* w_ih  = (const float*)d_in[7];
  const float* w_hh  = (const float*)d_in[8];
  const float* b_ih  = (const float*)d_in[9];
  const float* b_hh  = (const float*)d_in[10];
  const float* w1    = (const float*)d_in[11];
  const float* b1    = (const float*)d_in[12];
  const float* w2    = (const float*)d_in[13];
  const float* b2    = (const float*)d_in[14];
  const float* g_in  = (const float*)d_in[15];
  const float* bi_in = (const float*)d_in[16];
  const float* g_sl  = (const float*)d_in[17];
  const float* bi_sl = (const float*)d_in[18];
  const float* g_ml  = (const float*)d_in[19];
  const float* bi_ml = (const float*)d_in[20];

  float* ws      = (float*)d_ws;
  ushortT* ktF   = (ushortT*)(ws + OFF_KT);
  ushortT* vF    = (ushortT*)(ws + OFF_V);
  ushortT* qF    = (ushortT*)(ws + OFF_QT);
  float* part    = ws + OFF_PART;
  float* pcol    = ws + OFF_PCOL;
  float* sl      = ws + OFF_SLOTS;
  float* wihT    = ws + OFF_WIHT;
  float* whhT    = ws + OFF_WHHT;
  float* w1T     = ws + OFF_W1T;
  float* w2T     = ws + OFF_W2T;
  float* wqT     = ws + OFF_WQT;
  ushortT* wpk   = (ushortT*)(ws + OFF_WKV);
  int* cnt       = (int*)(ws + OFF_CNT);

  k_setup<<<208, 256, 0, stream>>>(w_ih, w_hh, w1, w2, Wq, Wk, Wv,
                                   noise, smu, slsig, g_sl, bi_sl,
                                   wihT, whhT, w1T, w2T, wqT, wpk,
                                   sl, qF, cnt);
  k_ln_project<<<4096, 256, 0, stream>>>(inp, wpk, g_in, bi_in, ktF, vF);
  k_attn_iter<<<1024, 256, 0, stream>>>(ktF, vF, qF, part, pcol, cnt, sl,
                                        wihT, whhT, w1T, w2T, wqT,
                                        b_ih, b_hh, b1, b2, g_ml, bi_ml, g_sl, bi_sl,
                                        (float*)d_out);
}